// Round 5
// baseline (387.456 us; speedup 1.0000x reference)
//
#include <hip/hip_runtime.h>
#include <hip/hip_bf16.h>
#include <stdint.h>

#define B_ 4
#define H_ 16
#define L_ 2048
#define D_ 64
#define BH (B_ * H_)

typedef __attribute__((ext_vector_type(8))) short short8;
typedef __attribute__((ext_vector_type(4))) float f32x4;

__device__ __forceinline__ short b16(float f) {
  __hip_bfloat16 h = __float2bfloat16(f);
  return __builtin_bit_cast(short, h);
}

// ---- prepass: V [bh][k][d] fp32 -> Vt [bh][d][k] bf16 (transposed) ----
__global__ __launch_bounds__(256) void vt_kernel(const float* __restrict__ V,
                                                 unsigned short* __restrict__ Vt) {
  __shared__ unsigned short lds[64 * 68];
  int bid = blockIdx.x;
  int bh  = bid >> 5;
  int kt  = bid & 31;
  int t   = threadIdx.x;
  const float* vsrc = V + ((size_t)bh * L_ + (size_t)kt * 64) * D_;
#pragma unroll
  for (int i = 0; i < 4; ++i) {
    int f4  = i * 256 + t;
    int row = f4 >> 4;
    int c4  = (f4 & 15) << 2;
    float4 v = *reinterpret_cast<const float4*>(vsrc + row * D_ + c4);
    ushort4 u;
    u.x = (unsigned short)b16(v.x);
    u.y = (unsigned short)b16(v.y);
    u.z = (unsigned short)b16(v.z);
    u.w = (unsigned short)b16(v.w);
    *reinterpret_cast<ushort4*>(&lds[row * 68 + c4]) = u;
  }
  __syncthreads();
  unsigned short* dst = Vt + (size_t)bh * D_ * L_ + (size_t)kt * 64;
#pragma unroll
  for (int i = 0; i < 8; ++i) {
    int c  = i * 256 + t;
    int d  = c >> 5;
    int k2 = (c & 31) * 2;
    unsigned int lo = lds[(k2 + 0) * 68 + d];
    unsigned int hi = lds[(k2 + 1) * 68 + d];
    *reinterpret_cast<unsigned int*>(dst + d * L_ + k2) = lo | (hi << 16);
  }
}

// ---- fused sigmoid-attention: dbuf K/V + reg-prefetch (T14), 2 barriers/iter ----
__global__ __launch_bounds__(256, 4) void attn4_kernel(
    const float* __restrict__ Q, const float* __restrict__ K,
    const int* __restrict__ M, const unsigned short* __restrict__ Vt,
    float* __restrict__ O, float* __restrict__ A) {
  __shared__ unsigned short Kl[2][4096];
  __shared__ unsigned short Vl[2][4096];
  __shared__ unsigned short Pl[4096];

  // XCD-aware decode: all 16 heads of a (b,qt) mask-tile on one XCD.
  int wg  = blockIdx.x;
  int xcd = wg & 7;
  int j   = wg >> 3;
  int g   = xcd * 16 + (j & 15);
  int b   = g >> 5;
  int qt  = g & 31;
  int h   = j >> 4;
  int bh  = b * 16 + h;

  int t    = threadIdx.x;
  int lane = t & 63;
  int w    = t >> 6;
  int wr   = w >> 1;
  int wc   = w & 1;
  int lr   = lane & 15;
  int lg   = lane >> 4;

  // Q fragments, temperature folded in
  short8 qf[2][2];
  const float* qbase = Q + ((size_t)bh * L_ + (size_t)qt * 64 + wr * 32) * D_;
#pragma unroll
  for (int m = 0; m < 2; ++m) {
#pragma unroll
    for (int ks = 0; ks < 2; ++ks) {
      const float4* p = reinterpret_cast<const float4*>(qbase + (m * 16 + lr) * D_ + ks * 32 + lg * 8);
      float4 a = p[0], c = p[1];
      qf[m][ks] = (short8){b16(a.x * 0.125f), b16(a.y * 0.125f), b16(a.z * 0.125f), b16(a.w * 0.125f),
                           b16(c.x * 0.125f), b16(c.y * 0.125f), b16(c.z * 0.125f), b16(c.w * 0.125f)};
    }
  }

  f32x4 o[2][2] = {};
  const int* mbase = M + (size_t)b * L_ * L_;
  float* abase = A + (size_t)bh * L_ * L_;
  const float* kbase0 = K + (size_t)bh * L_ * D_;
  const unsigned short* vbase0 = Vt + (size_t)bh * D_ * L_;
  int qrow = qt * 64 + wr * 32;

  // staging geometry (per thread): K: 4 rows of float4; V: 2 rows of uint4
  int krow[4], kc4[4];
#pragma unroll
  for (int i = 0; i < 4; ++i) {
    int f4  = i * 256 + t;
    krow[i] = f4 >> 4;
    kc4[i]  = (f4 & 15) << 2;
  }
  int vrow[2], vc0[2];
#pragma unroll
  for (int i = 0; i < 2; ++i) {
    int gi  = i * 256 + t;
    vrow[i] = gi >> 3;
    vc0[i]  = (gi & 7) << 3;
  }

  float4 kreg[4];
  uint4  vreg[2];

  // prologue: load tile 0 -> regs -> LDS buf 0
#pragma unroll
  for (int i = 0; i < 4; ++i)
    kreg[i] = *reinterpret_cast<const float4*>(kbase0 + krow[i] * D_ + kc4[i]);
#pragma unroll
  for (int i = 0; i < 2; ++i)
    vreg[i] = *reinterpret_cast<const uint4*>(vbase0 + (size_t)vrow[i] * L_ + vc0[i]);
#pragma unroll
  for (int i = 0; i < 4; ++i) {
    ushort4 u;
    u.x = (unsigned short)b16(kreg[i].x);
    u.y = (unsigned short)b16(kreg[i].y);
    u.z = (unsigned short)b16(kreg[i].z);
    u.w = (unsigned short)b16(kreg[i].w);
    *reinterpret_cast<ushort4*>(&Kl[0][krow[i] * 64 + (kc4[i] ^ ((krow[i] & 7) << 3))]) = u;
  }
#pragma unroll
  for (int i = 0; i < 2; ++i)
    *reinterpret_cast<uint4*>(&Vl[0][vrow[i] * 64 + (vc0[i] ^ ((vrow[i] & 7) << 3))]) = vreg[i];

  for (int ki = 0; ki < 32; ++ki) {
    int cur = ki & 1;
    int k0  = ki * 64;

    __syncthreads();  // BARRIER_1: tile-ki LDS writes visible; prev Pl readers done

    // issue next-tile global loads early (latency hides under QK + sigmoid + PV)
    if (ki + 1 < 32) {
      const float* ksrc = kbase0 + (size_t)(k0 + 64) * D_;
      const unsigned short* vsrc = vbase0 + k0 + 64;
#pragma unroll
      for (int i = 0; i < 4; ++i)
        kreg[i] = *reinterpret_cast<const float4*>(ksrc + krow[i] * D_ + kc4[i]);
#pragma unroll
      for (int i = 0; i < 2; ++i)
        vreg[i] = *reinterpret_cast<const uint4*>(vsrc + (size_t)vrow[i] * L_ + vc0[i]);
    }

    // mask: one int4 per 16x16 tile
    int4 mv[2][2];
#pragma unroll
    for (int m = 0; m < 2; ++m)
#pragma unroll
      for (int n = 0; n < 2; ++n)
        mv[m][n] = *reinterpret_cast<const int4*>(
            mbase + (size_t)(qrow + m * 16 + lr) * L_ + k0 + wc * 32 + n * 16 + lg * 4);

    // ---- S^T = K Q^T ----
    f32x4 s[2][2] = {};
#pragma unroll
    for (int ks = 0; ks < 2; ++ks) {
      short8 kf[2];
#pragma unroll
      for (int n = 0; n < 2; ++n) {
        int row = wc * 32 + n * 16 + lr;
        int col = ks * 32 + lg * 8;
        kf[n] = *reinterpret_cast<const short8*>(&Kl[cur][row * 64 + (col ^ ((row & 7) << 3))]);
      }
#pragma unroll
      for (int m = 0; m < 2; ++m)
#pragma unroll
        for (int n = 0; n < 2; ++n)
          s[m][n] = __builtin_amdgcn_mfma_f32_16x16x32_bf16(kf[n], qf[m][ks], s[m][n], 0, 0, 0);
    }

    // ---- mask + sigmoid; attn f32x4 nt-store; P ushort4 LDS write ----
#pragma unroll
    for (int m = 0; m < 2; ++m) {
#pragma unroll
      for (int n = 0; n < 2; ++n) {
        f32x4 f;
        ushort4 u;
#pragma unroll
        for (int r = 0; r < 4; ++r) {
          float sv = s[m][n][r];
          float e  = __builtin_amdgcn_exp2f(sv * -1.44269504f);
          float at = ((&mv[m][n].x)[r] != 0)
                         ? __builtin_amdgcn_rcpf(1.0f + e)
                         : 0.0f;
          f[r] = at;
          (&u.x)[r] = (unsigned short)b16(at);
        }
        __builtin_nontemporal_store(f, reinterpret_cast<f32x4*>(
            abase + (size_t)(qrow + m * 16 + lr) * L_ + k0 + wc * 32 + n * 16 + lg * 4));
        int q  = wr * 32 + m * 16 + lr;
        int kl = wc * 32 + n * 16 + lg * 4;
        *reinterpret_cast<ushort4*>(&Pl[q * 64 + (kl ^ ((q & 7) << 3))]) = u;
      }
    }
    __syncthreads();  // BARRIER_2: P visible

    // ---- O += P V ----
#pragma unroll
    for (int ks = 0; ks < 2; ++ks) {
      short8 pf[2], vf[2];
#pragma unroll
      for (int m = 0; m < 2; ++m) {
        int row = wr * 32 + m * 16 + lr;
        int col = ks * 32 + lg * 8;
        pf[m] = *reinterpret_cast<const short8*>(&Pl[row * 64 + (col ^ ((row & 7) << 3))]);
      }
#pragma unroll
      for (int n = 0; n < 2; ++n) {
        int row = wc * 32 + n * 16 + lr;
        int col = ks * 32 + lg * 8;
        vf[n] = *reinterpret_cast<const short8*>(&Vl[cur][row * 64 + (col ^ ((row & 7) << 3))]);
      }
#pragma unroll
      for (int m = 0; m < 2; ++m)
#pragma unroll
        for (int n = 0; n < 2; ++n)
          o[m][n] = __builtin_amdgcn_mfma_f32_16x16x32_bf16(pf[m], vf[n], o[m][n], 0, 0, 0);
    }

    // ---- write next tile regs -> other LDS buffer (vmcnt satisfied long ago) ----
    if (ki + 1 < 32) {
#pragma unroll
      for (int i = 0; i < 4; ++i) {
        ushort4 u;
        u.x = (unsigned short)b16(kreg[i].x);
        u.y = (unsigned short)b16(kreg[i].y);
        u.z = (unsigned short)b16(kreg[i].z);
        u.w = (unsigned short)b16(kreg[i].w);
        *reinterpret_cast<ushort4*>(&Kl[cur ^ 1][krow[i] * 64 + (kc4[i] ^ ((krow[i] & 7) << 3))]) = u;
      }
#pragma unroll
      for (int i = 0; i < 2; ++i)
        *reinterpret_cast<uint4*>(&Vl[cur ^ 1][vrow[i] * 64 + (vc0[i] ^ ((vrow[i] & 7) << 3))]) = vreg[i];
    }
  }

  // ---- epilogue: write O ----
  float* obase = O + ((size_t)bh * L_ + (size_t)qt * 64 + wr * 32) * D_;
#pragma unroll
  for (int m = 0; m < 2; ++m)
#pragma unroll
    for (int n = 0; n < 2; ++n)
#pragma unroll
      for (int r = 0; r < 4; ++r)
        __builtin_nontemporal_store(o[m][n][r],
            &obase[(m * 16 + lg * 4 + r) * D_ + wc * 32 + n * 16 + lr]);
}

extern "C" void kernel_launch(void* const* d_in, const int* in_sizes, int n_in,
                              void* d_out, int out_size, void* d_ws, size_t ws_size,
                              hipStream_t stream) {
  (void)in_sizes; (void)n_in; (void)out_size; (void)ws_size;
  const float* Q = (const float*)d_in[0];
  const float* K = (const float*)d_in[1];
  const float* V = (const float*)d_in[2];
  const int*   M = (const int*)d_in[3];
  float* O = (float*)d_out;
  float* A = (float*)d_out + (size_t)BH * L_ * D_;
  unsigned short* Vt = (unsigned short*)d_ws;  // 16.8 MB scratch

  vt_kernel<<<BH * 32, 256, 0, stream>>>(V, Vt);
  attn4_kernel<<<BH * 32, 256, 0, stream>>>(Q, K, M, Vt, O, A);
}